// Round 10
// baseline (459.485 us; speedup 1.0000x reference)
//
#include <hip/hip_runtime.h>
#include <math.h>

#define B_SZ 2
#define L_SZ 2048
#define DMODEL 1024
#define DINNER 2048
#define DSTATE 16
#define DCONV 4
#define DTRANK 64

#define CS 32                    // scan chunk size
#define NCH (L_SZ / CS)          // 64 chunks per batch

typedef float f32x4 __attribute__((ext_vector_type(4)));
typedef __bf16 bf16x8 __attribute__((ext_vector_type(8)));

__device__ __forceinline__ float silu_f(float x) {
    return x / (1.0f + __expf(-x));
}

__device__ __forceinline__ float softplus_f(float x) {
    return (x > 20.0f) ? x : log1pf(expf(x));
}

// fp32 -> bf16 round-to-nearest-even on raw bits
__device__ __forceinline__ unsigned short f2bf(float x) {
    unsigned int u = __float_as_uint(x);
    u = u + 0x7FFFu + ((u >> 16) & 1u);
    return (unsigned short)(u >> 16);
}

__device__ __forceinline__ float bf2f(unsigned short s) {
    return __uint_as_float(((unsigned int)s) << 16);
}

// async global->LDS DMA, 16B per lane; deposits at base + lane*16B.
__device__ __forceinline__ void gload_lds16(const unsigned short* g, unsigned short* l) {
    __builtin_amdgcn_global_load_lds(
        (const __attribute__((address_space(1))) void*)g,
        (__attribute__((address_space(3))) void*)l, 16, 0, 0);
}

union Pack8 { unsigned short s[8]; uint4 v; };

// Transpose + cast: W[R,C] fp32 -> WT[C,R] bf16. Grid (C/32, R/32), 256 thr.
__global__ __launch_bounds__(256) void transpose_cast(
    const float* __restrict__ W, unsigned short* __restrict__ WT, int R, int C)
{
    __shared__ float t[32][33];
    const int tx = threadIdx.x & 31;
    const int ty = threadIdx.x >> 5;
    const int r0 = blockIdx.y * 32;
    const int c0 = blockIdx.x * 32;
    #pragma unroll
    for (int i = 0; i < 4; i++)
        t[ty + i * 8][tx] = W[(r0 + ty + i * 8) * C + c0 + tx];
    __syncthreads();
    #pragma unroll
    for (int i = 0; i < 4; i++)
        WT[(c0 + ty + i * 8) * R + r0 + tx] = f2bf(t[tx][ty + i * 8]);
}

// cast fp32 -> bf16, 8 elems/thread
__global__ __launch_bounds__(256) void cast_bf16(
    const float* __restrict__ src, unsigned short* __restrict__ dst, int n8)
{
    int i = blockIdx.x * 256 + threadIdx.x;
    if (i >= n8) return;
    const float4 f0 = *(const float4*)(src + i * 8);
    const float4 f1 = *(const float4*)(src + i * 8 + 4);
    Pack8 p;
    p.s[0] = f2bf(f0.x); p.s[1] = f2bf(f0.y); p.s[2] = f2bf(f0.z); p.s[3] = f2bf(f0.w);
    p.s[4] = f2bf(f1.x); p.s[5] = f2bf(f1.y); p.s[6] = f2bf(f1.z); p.s[7] = f2bf(f1.w);
    *(uint4*)(dst + i * 8) = p.v;
}

// ---- bf16 MFMA GEMM, B pre-transposed, global_load_lds staging -------------
// C[M,N] = A[M,K](bf16) @ BT[N,K](bf16)^T, fp32 accumulate.
// BK=64, XOR-swizzled LDS (conflict-free b128 reads, no padding needed).
// Tile 128x128, 4 waves (2x2), 64x64/wave via mfma_f32_16x16x32_bf16.
// Split-K via gridDim.z (Kc multiple of 64). B row clamped to N-1.
template <int ACT, int OBF16>
__global__ __launch_bounds__(256) void gemm_bt_lds(
    const unsigned short* __restrict__ A, const unsigned short* __restrict__ BT,
    void* __restrict__ Cout, const float* __restrict__ bias,
    int M, int N, int K, int lda, int ldb, int ldc, int Kc)
{
    __shared__ unsigned short As[128 * 64];
    __shared__ unsigned short Bs[128 * 64];

    const int tid  = threadIdx.x;
    const int lane = tid & 63;
    const int wave = tid >> 6;
    const int wm   = wave >> 1;
    const int wn   = wave & 1;
    const int row0 = blockIdx.y * 128;
    const int col0 = blockIdx.x * 128;
    const int lq   = lane >> 4;
    const int lm   = lane & 15;
    const int kbeg = blockIdx.z * Kc;

    const int rloc = wave * 32 + (lane >> 3);
    const int sc   = (lane & 7) ^ ((lane >> 3) & 7);
    const unsigned short* gA = A + (size_t)(row0 + rloc) * lda + sc * 8;
    const unsigned short* gBp[4];
    #pragma unroll
    for (int is = 0; is < 4; is++) {
        int br = col0 + rloc + 8 * is;
        if (br > N - 1) br = N - 1;
        gBp[is] = BT + (size_t)br * ldb + sc * 8;
    }
    unsigned short* lA = As + wave * 2048;
    unsigned short* lB = Bs + wave * 2048;

    f32x4 acc[4][4];
    #pragma unroll
    for (int i = 0; i < 4; i++)
        #pragma unroll
        for (int j = 0; j < 4; j++)
            #pragma unroll
            for (int r = 0; r < 4; r++) acc[i][j][r] = 0.0f;

    for (int k0 = kbeg; k0 < kbeg + Kc; k0 += 64) {
        #pragma unroll
        for (int is = 0; is < 4; is++) {
            gload_lds16(gA + (size_t)(8 * is) * lda + k0, lA + is * 512);
            gload_lds16(gBp[is] + k0, lB + is * 512);
        }
        __syncthreads();

        #pragma unroll
        for (int ks = 0; ks < 2; ks++) {
            bf16x8 af[4], bfr[4];
            #pragma unroll
            for (int i = 0; i < 4; i++) {
                int row = wm * 64 + i * 16 + lm;
                af[i] = *(const bf16x8*)&As[row * 64 + (((ks * 4 + lq) ^ (row & 7)) * 8)];
            }
            #pragma unroll
            for (int j = 0; j < 4; j++) {
                int row = wn * 64 + j * 16 + lm;
                bfr[j] = *(const bf16x8*)&Bs[row * 64 + (((ks * 4 + lq) ^ (row & 7)) * 8)];
            }
            #pragma unroll
            for (int i = 0; i < 4; i++)
                #pragma unroll
                for (int j = 0; j < 4; j++)
                    acc[i][j] = __builtin_amdgcn_mfma_f32_16x16x32_bf16(
                        af[i], bfr[j], acc[i][j], 0, 0, 0);
        }
        __syncthreads();
    }

    // epilogue: C/D layout col=lane&15, row=(lane>>4)*4+reg
    #pragma unroll
    for (int i = 0; i < 4; i++) {
        #pragma unroll
        for (int r = 0; r < 4; r++) {
            int row = row0 + wm * 64 + i * 16 + lq * 4 + r;
            #pragma unroll
            for (int j = 0; j < 4; j++) {
                int col = col0 + wn * 64 + j * 16 + lm;
                if (col < N) {
                    float v = acc[i][j][r];
                    if (ACT == 1) v = softplus_f(v + bias[col]);
                    if (OBF16) {
                        unsigned short* Cz = (unsigned short*)Cout +
                            (size_t)blockIdx.z * (size_t)M * ldc;
                        Cz[(size_t)row * ldc + col] = f2bf(v);
                    } else {
                        float* Cz = (float*)Cout +
                            (size_t)blockIdx.z * (size_t)M * ldc;
                        Cz[(size_t)row * ldc + col] = v;
                    }
                }
            }
        }
    }
}

// Sum nsplit partial C buffers; also emit bf16 copy of cols<64 (dt_lo).
__global__ __launch_bounds__(256) void reduce_splitk(
    const float* __restrict__ part, float* __restrict__ C,
    unsigned short* __restrict__ dtlo16, int n, int nsplit)
{
    int i = blockIdx.x * 256 + threadIdx.x;
    if (i >= n) return;
    float s = 0.0f;
    for (int z = 0; z < nsplit; z++) s += part[(size_t)z * n + i];
    C[i] = s;
    int row = i / 96;
    int col = i - row * 96;
    if (col < DTRANK) dtlo16[row * DTRANK + col] = f2bf(s);
}

// conv + silu, register-rolling window along l. Reads bf16 xz (cols 0..2048),
// emits bf16 xc16. grid (8, 64, 2).
__global__ __launch_bounds__(256) void conv_silu_v2(
    const unsigned short* __restrict__ xz16, const float* __restrict__ conv_w,
    const float* __restrict__ conv_b, unsigned short* __restrict__ xc16)
{
    const int tid = threadIdx.x;
    const int d   = blockIdx.x * 256 + tid;
    const int l0  = blockIdx.y * 32;
    const int b   = blockIdx.z;
    const float4 w  = *(const float4*)(conv_w + d * 4);
    const float bias = conv_b[d];
    const int t0 = b * L_SZ + l0;
    const unsigned short* src = xz16 + (size_t)t0 * 4096 + d;

    float r0, r1, r2;
    if (l0 == 0) {
        r0 = r1 = r2 = 0.0f;
    } else {
        r0 = bf2f(src[-3 * 4096]);
        r1 = bf2f(src[-2 * 4096]);
        r2 = bf2f(src[-1 * 4096]);
    }
    #pragma unroll 4
    for (int l = 0; l < 32; l++) {
        float r3 = bf2f(src[(size_t)l * 4096]);
        float acc = bias + r0 * w.x + r1 * w.y + r2 * w.z + r3 * w.w;
        xc16[(size_t)(t0 + l) * DINNER + d] = f2bf(silu_f(acc));
        r0 = r1; r1 = r2; r2 = r3;
    }
}

// ---- Chunked parallel selective scan (CS=32, 1024 blocks) -------------------
// grid: B * NCH * 8 = 2*64*8 = 1024; db=blk&7, c=(blk>>3)&63, b=blk>>9.
__global__ __launch_bounds__(256) void scan_pass1(
    const unsigned short* __restrict__ xc16, const float* __restrict__ delta,
    const float* __restrict__ dbc, const float* __restrict__ A_log,
    float* __restrict__ P, float* __restrict__ E)
{
    __shared__ float Bs[CS * DSTATE];
    const int tid = threadIdx.x;
    const int db  = blockIdx.x & 7;
    const int c   = (blockIdx.x >> 3) & (NCH - 1);
    const int b   = blockIdx.x >> 9;
    const int d   = db * 256 + tid;
    const int t0  = b * L_SZ + c * CS;

    for (int idx = tid; idx < CS * DSTATE; idx += 256) {
        int step = idx >> 4, i = idx & 15;
        Bs[idx] = dbc[(t0 + step) * 96 + DTRANK + i];
    }

    float A[DSTATE], Er[DSTATE];
    #pragma unroll
    for (int s = 0; s < DSTATE; s++) {
        A[s]  = -__expf(A_log[d * DSTATE + s]);
        Er[s] = 0.0f;
    }
    float sd = 0.0f;
    __syncthreads();

    for (int l = 0; l < CS; l++) {
        const int t = t0 + l;
        float dv = delta[t * DINNER + d];
        float uv = bf2f(xc16[(size_t)t * DINNER + d]);
        float du = dv * uv;
        sd += dv;
        #pragma unroll
        for (int s = 0; s < DSTATE; s++) {
            float dA = __expf(dv * A[s]);
            Er[s] = dA * Er[s] + du * Bs[l * DSTATE + s];
        }
    }

    const long long o = ((long long)((b * NCH + c) * DINNER) + d) * DSTATE;
    #pragma unroll
    for (int s = 0; s < DSTATE; s++) {
        P[o + s] = __expf(A[s] * sd);
        E[o + s] = Er[s];
    }
}

__global__ __launch_bounds__(256) void scan_pass2(
    const float* __restrict__ P, float* __restrict__ E)
{
    const int gid  = blockIdx.x * 256 + threadIdx.x;
    const int b    = gid >> 15;
    const int rest = gid & 32767;
    float h = 0.0f;
    for (int c = 0; c < NCH; c++) {
        const long long idx = (long long)(b * NCH + c) * (DINNER * DSTATE) + rest;
        float p = P[idx];
        float e = E[idx];
        E[idx] = h;
        h = p * h + e;
    }
}

// pass3: emit y in bf16, fused silu(z) gate (z from bf16 xz cols 2048..4096).
__global__ __launch_bounds__(256) void scan_pass3(
    const unsigned short* __restrict__ xc16, const float* __restrict__ delta,
    const float* __restrict__ dbc, const float* __restrict__ A_log,
    const float* __restrict__ D_skip, const float* __restrict__ Hin,
    const unsigned short* __restrict__ xz16, unsigned short* __restrict__ y16)
{
    __shared__ float BCs[CS * 2 * DSTATE];
    const int tid = threadIdx.x;
    const int db  = blockIdx.x & 7;
    const int c   = (blockIdx.x >> 3) & (NCH - 1);
    const int b   = blockIdx.x >> 9;
    const int d   = db * 256 + tid;
    const int t0  = b * L_SZ + c * CS;

    for (int idx = tid; idx < CS * 2 * DSTATE; idx += 256) {
        int step = idx >> 5, i = idx & 31;
        BCs[idx] = dbc[(t0 + step) * 96 + DTRANK + i];
    }

    float A[DSTATE], h[DSTATE];
    const long long o = ((long long)((b * NCH + c) * DINNER) + d) * DSTATE;
    #pragma unroll
    for (int s = 0; s < DSTATE; s++) {
        A[s] = -__expf(A_log[d * DSTATE + s]);
        h[s] = Hin[o + s];
    }
    const float Dv = D_skip[d];
    __syncthreads();

    for (int l = 0; l < CS; l++) {
        const int t = t0 + l;
        float dv = delta[t * DINNER + d];
        float uv = bf2f(xc16[(size_t)t * DINNER + d]);
        float du = dv * uv;
        float yv = 0.0f;
        #pragma unroll
        for (int s = 0; s < DSTATE; s++) {
            float dA = __expf(dv * A[s]);
            h[s] = dA * h[s] + du * BCs[l * 32 + s];
            yv  += h[s] * BCs[l * 32 + DSTATE + s];
        }
        float z = bf2f(xz16[(size_t)t * 4096 + DINNER + d]);
        y16[t * DINNER + d] = f2bf((uv * Dv + yv) * silu_f(z));
    }
}

extern "C" void kernel_launch(void* const* d_in, const int* in_sizes, int n_in,
                              void* d_out, int out_size, void* d_ws, size_t ws_size,
                              hipStream_t stream) {
    const float* x       = (const float*)d_in[0];
    const float* W_in    = (const float*)d_in[1];
    const float* conv_w  = (const float*)d_in[2];
    const float* conv_b  = (const float*)d_in[3];
    const float* W_xproj = (const float*)d_in[4];
    const float* W_dt    = (const float*)d_in[5];
    const float* b_dt    = (const float*)d_in[6];
    const float* A_log   = (const float*)d_in[7];
    const float* D_skip  = (const float*)d_in[8];
    const float* W_out   = (const float*)d_in[9];
    float* out = (float*)d_out;

    // workspace layout, float units (141 MB). Aliases (both dead-before-reuse):
    //   parts (dead after reduce) shares the Pbuf region (written at pass1)
    //   x16 (dead after gemm1)    shares yb16 (written at pass3)
    float* ws = (float*)d_ws;
    unsigned short* xz16   = (unsigned short*)ws;              // [0 .. 8388608) f
    unsigned short* xc16   = (unsigned short*)(ws +  8388608); // [8388608 .. 12582912) f
    float* dbc             = ws + 12582912;                    // [.. 12976128) f
    unsigned short* dtlo16 = (unsigned short*)(ws + 12976128); // [.. 13107200) f
    float* delta           = ws + 13107200;                    // [.. 21495808) f
    float* Ebuf            = ws + 21495808;                    // [.. 25690112) f : 2*64*2048*16
    float* Pbuf            = ws + 25690112;                    // [.. 29884416) f : 2*64*2048*16
    float* parts           = Pbuf;                             //   alias, needs 3145728 f < 4194304 ✓
    unsigned short* yb16   = (unsigned short*)(ws + 29884416); // [.. 31981568) f
    unsigned short* x16    = yb16;                             //   alias
    unsigned short* W_inT    = (unsigned short*)(ws + 31981568); // [.. 34078720) f
    unsigned short* W_xprojT = (unsigned short*)(ws + 34078720); // [.. 34177024) f
    unsigned short* W_dtT    = (unsigned short*)(ws + 34177024); // [.. 34242560) f
    unsigned short* W_outT   = (unsigned short*)(ws + 34242560); // [.. 35291136) f

    const int MT = 4096;  // B*L tokens

    transpose_cast<<<dim3(128, 32), 256, 0, stream>>>(W_in,    W_inT,    1024, 4096);
    transpose_cast<<<dim3(  3, 64), 256, 0, stream>>>(W_xproj, W_xprojT, 2048,   96);
    transpose_cast<<<dim3( 64,  2), 256, 0, stream>>>(W_dt,    W_dtT,      64, 2048);
    transpose_cast<<<dim3( 32, 64), 256, 0, stream>>>(W_out,   W_outT,   2048, 1024);
    cast_bf16<<<dim3(2048), 256, 0, stream>>>(x, x16, 524288);

    // 1) xz = x @ W_in              (4096 x 4096, K=1024) -> bf16
    gemm_bt_lds<0, 1><<<dim3(32, 32), 256, 0, stream>>>(
        x16, W_inT, xz16, nullptr, MT, 4096, 1024, 1024, 1024, 4096, 1024);

    // 2) xc16 = silu(causal_dwconv(xin) + b)
    conv_silu_v2<<<dim3(8, 64, 2), 256, 0, stream>>>(xz16, conv_w, conv_b, xc16);

    // 3) dbc = xc @ W_xproj         (4096 x 96, K=2048) — split-K x8
    gemm_bt_lds<0, 0><<<dim3(1, 32, 8), 256, 0, stream>>>(
        xc16, W_xprojT, parts, nullptr, MT, 96, 2048, 2048, 2048, 96, 256);
    reduce_splitk<<<dim3(1536), 256, 0, stream>>>(parts, dbc, dtlo16, MT * 96, 8);

    // 4) delta = softplus(dt_lo @ W_dt + b_dt)  (4096 x 2048, K=64)
    gemm_bt_lds<1, 0><<<dim3(16, 32), 256, 0, stream>>>(
        dtlo16, W_dtT, delta, b_dt, MT, 2048, 64, 64, 64, 2048, 64);

    // 5) chunked selective scan + fused gate (bf16 y out)
    scan_pass1<<<dim3(1024), 256, 0, stream>>>(xc16, delta, dbc, A_log, Pbuf, Ebuf);
    scan_pass2<<<dim3(256), 256, 0, stream>>>(Pbuf, Ebuf);
    scan_pass3<<<dim3(1024), 256, 0, stream>>>(xc16, delta, dbc, A_log, D_skip,
                                               Ebuf, xz16, yb16);

    // 6) out = y @ W_out            (4096 x 1024, K=2048)
    gemm_bt_lds<0, 0><<<dim3(8, 32), 256, 0, stream>>>(
        yb16, W_outT, out, nullptr, MT, 1024, 2048, 2048, 2048, 1024, 2048);
}

// Round 11
// 343.450 us; speedup vs baseline: 1.3379x; 1.3379x over previous
//
#include <hip/hip_runtime.h>
#include <math.h>

#define B_SZ 2
#define L_SZ 2048
#define DMODEL 1024
#define DINNER 2048
#define DSTATE 16
#define DCONV 4
#define DTRANK 64

#define CS 64                    // scan chunk size
#define NCH (L_SZ / CS)          // 32 chunks per batch

typedef float f32x4 __attribute__((ext_vector_type(4)));
typedef __bf16 bf16x8 __attribute__((ext_vector_type(8)));

__device__ __forceinline__ float silu_f(float x) {
    return x / (1.0f + __expf(-x));
}

// fast softplus: max(x,0) + log(1+exp(-|x|)); abs err ~1e-6, branch-free tails
__device__ __forceinline__ float softplus_f(float x) {
    return fmaxf(x, 0.0f) + __logf(1.0f + __expf(-fabsf(x)));
}

// fp32 -> bf16 round-to-nearest-even on raw bits
__device__ __forceinline__ unsigned short f2bf(float x) {
    unsigned int u = __float_as_uint(x);
    u = u + 0x7FFFu + ((u >> 16) & 1u);
    return (unsigned short)(u >> 16);
}

__device__ __forceinline__ float bf2f(unsigned short s) {
    return __uint_as_float(((unsigned int)s) << 16);
}

// async global->LDS DMA, 16B per lane; deposits at base + lane*16B.
__device__ __forceinline__ void gload_lds16(const unsigned short* g, unsigned short* l) {
    __builtin_amdgcn_global_load_lds(
        (const __attribute__((address_space(1))) void*)g,
        (__attribute__((address_space(3))) void*)l, 16, 0, 0);
}

union Pack8 { unsigned short s[8]; uint4 v; };

// Transpose + cast: W[R,C] fp32 -> WT[C,R] bf16. Grid (C/32, R/32), 256 thr.
__global__ __launch_bounds__(256) void transpose_cast(
    const float* __restrict__ W, unsigned short* __restrict__ WT, int R, int C)
{
    __shared__ float t[32][33];
    const int tx = threadIdx.x & 31;
    const int ty = threadIdx.x >> 5;
    const int r0 = blockIdx.y * 32;
    const int c0 = blockIdx.x * 32;
    #pragma unroll
    for (int i = 0; i < 4; i++)
        t[ty + i * 8][tx] = W[(r0 + ty + i * 8) * C + c0 + tx];
    __syncthreads();
    #pragma unroll
    for (int i = 0; i < 4; i++)
        WT[(c0 + ty + i * 8) * R + r0 + tx] = f2bf(t[tx][ty + i * 8]);
}

// cast fp32 -> bf16, 8 elems/thread
__global__ __launch_bounds__(256) void cast_bf16(
    const float* __restrict__ src, unsigned short* __restrict__ dst, int n8)
{
    int i = blockIdx.x * 256 + threadIdx.x;
    if (i >= n8) return;
    const float4 f0 = *(const float4*)(src + i * 8);
    const float4 f1 = *(const float4*)(src + i * 8 + 4);
    Pack8 p;
    p.s[0] = f2bf(f0.x); p.s[1] = f2bf(f0.y); p.s[2] = f2bf(f0.z); p.s[3] = f2bf(f0.w);
    p.s[4] = f2bf(f1.x); p.s[5] = f2bf(f1.y); p.s[6] = f2bf(f1.z); p.s[7] = f2bf(f1.w);
    *(uint4*)(dst + i * 8) = p.v;
}

// ---- bf16 MFMA GEMM, B pre-transposed, global_load_lds staging -------------
// C[M,N] = A[M,K](bf16) @ BT[N,K](bf16)^T, fp32 accumulate.
// BK=64, XOR-swizzled LDS: dest row r's LDS chunk c holds source 16B-chunk
// c^(r&7) -> conflict-free b128 fragment reads without padding.
// Tile 128x128, 4 waves (2x2), 64x64/wave via mfma_f32_16x16x32_bf16.
// Split-K via gridDim.z (Kc multiple of 64). B row clamped to N-1.
template <int ACT, int OBF16>
__global__ __launch_bounds__(256) void gemm_bt_lds(
    const unsigned short* __restrict__ A, const unsigned short* __restrict__ BT,
    void* __restrict__ Cout, const float* __restrict__ bias,
    int M, int N, int K, int lda, int ldb, int ldc, int Kc)
{
    __shared__ unsigned short As[128 * 64];
    __shared__ unsigned short Bs[128 * 64];

    const int tid  = threadIdx.x;
    const int lane = tid & 63;
    const int wave = tid >> 6;
    const int wm   = wave >> 1;
    const int wn   = wave & 1;
    const int row0 = blockIdx.y * 128;
    const int col0 = blockIdx.x * 128;
    const int lq   = lane >> 4;
    const int lm   = lane & 15;
    const int kbeg = blockIdx.z * Kc;

    const int rloc = wave * 32 + (lane >> 3);
    const int sc   = (lane & 7) ^ ((lane >> 3) & 7);
    const unsigned short* gA = A + (size_t)(row0 + rloc) * lda + sc * 8;
    const unsigned short* gBp[4];
    #pragma unroll
    for (int is = 0; is < 4; is++) {
        int br = col0 + rloc + 8 * is;
        if (br > N - 1) br = N - 1;
        gBp[is] = BT + (size_t)br * ldb + sc * 8;
    }
    unsigned short* lA = As + wave * 2048;
    unsigned short* lB = Bs + wave * 2048;

    f32x4 acc[4][4];
    #pragma unroll
    for (int i = 0; i < 4; i++)
        #pragma unroll
        for (int j = 0; j < 4; j++)
            #pragma unroll
            for (int r = 0; r < 4; r++) acc[i][j][r] = 0.0f;

    for (int k0 = kbeg; k0 < kbeg + Kc; k0 += 64) {
        #pragma unroll
        for (int is = 0; is < 4; is++) {
            gload_lds16(gA + (size_t)(8 * is) * lda + k0, lA + is * 512);
            gload_lds16(gBp[is] + k0, lB + is * 512);
        }
        __syncthreads();

        #pragma unroll
        for (int ks = 0; ks < 2; ks++) {
            bf16x8 af[4], bfr[4];
            #pragma unroll
            for (int i = 0; i < 4; i++) {
                int row = wm * 64 + i * 16 + lm;
                af[i] = *(const bf16x8*)&As[row * 64 + (((ks * 4 + lq) ^ (row & 7)) * 8)];
            }
            #pragma unroll
            for (int j = 0; j < 4; j++) {
                int row = wn * 64 + j * 16 + lm;
                bfr[j] = *(const bf16x8*)&Bs[row * 64 + (((ks * 4 + lq) ^ (row & 7)) * 8)];
            }
            #pragma unroll
            for (int i = 0; i < 4; i++)
                #pragma unroll
                for (int j = 0; j < 4; j++)
                    acc[i][j] = __builtin_amdgcn_mfma_f32_16x16x32_bf16(
                        af[i], bfr[j], acc[i][j], 0, 0, 0);
        }
        __syncthreads();
    }

    // epilogue: C/D layout col=lane&15, row=(lane>>4)*4+reg
    #pragma unroll
    for (int i = 0; i < 4; i++) {
        #pragma unroll
        for (int r = 0; r < 4; r++) {
            int row = row0 + wm * 64 + i * 16 + lq * 4 + r;
            #pragma unroll
            for (int j = 0; j < 4; j++) {
                int col = col0 + wn * 64 + j * 16 + lm;
                if (col < N) {
                    float v = acc[i][j][r];
                    if (ACT == 1) v = softplus_f(v + bias[col]);
                    if (OBF16) {
                        unsigned short* Cz = (unsigned short*)Cout +
                            (size_t)blockIdx.z * (size_t)M * ldc;
                        Cz[(size_t)row * ldc + col] = f2bf(v);
                    } else {
                        float* Cz = (float*)Cout +
                            (size_t)blockIdx.z * (size_t)M * ldc;
                        Cz[(size_t)row * ldc + col] = v;
                    }
                }
            }
        }
    }
}

// Sum nsplit partial C buffers; also emit bf16 copy of cols<64 (dt_lo).
__global__ __launch_bounds__(256) void reduce_splitk(
    const float* __restrict__ part, float* __restrict__ C,
    unsigned short* __restrict__ dtlo16, int n, int nsplit)
{
    int i = blockIdx.x * 256 + threadIdx.x;
    if (i >= n) return;
    float s = 0.0f;
    for (int z = 0; z < nsplit; z++) s += part[(size_t)z * n + i];
    C[i] = s;
    int row = i / 96;
    int col = i - row * 96;
    if (col < DTRANK) dtlo16[row * DTRANK + col] = f2bf(s);
}

// conv + silu, register-rolling window along l. Reads bf16 xz (cols 0..2048),
// emits bf16 xc16. grid (8, 64, 2).
__global__ __launch_bounds__(256) void conv_silu_v2(
    const unsigned short* __restrict__ xz16, const float* __restrict__ conv_w,
    const float* __restrict__ conv_b, unsigned short* __restrict__ xc16)
{
    const int tid = threadIdx.x;
    const int d   = blockIdx.x * 256 + tid;
    const int l0  = blockIdx.y * 32;
    const int b   = blockIdx.z;
    const float4 w  = *(const float4*)(conv_w + d * 4);
    const float bias = conv_b[d];
    const int t0 = b * L_SZ + l0;
    const unsigned short* src = xz16 + (size_t)t0 * 4096 + d;

    float r0, r1, r2;
    if (l0 == 0) {
        r0 = r1 = r2 = 0.0f;
    } else {
        r0 = bf2f(src[-3 * 4096]);
        r1 = bf2f(src[-2 * 4096]);
        r2 = bf2f(src[-1 * 4096]);
    }
    #pragma unroll 4
    for (int l = 0; l < 32; l++) {
        float r3 = bf2f(src[(size_t)l * 4096]);
        float acc = bias + r0 * w.x + r1 * w.y + r2 * w.z + r3 * w.w;
        xc16[(size_t)(t0 + l) * DINNER + d] = f2bf(silu_f(acc));
        r0 = r1; r1 = r2; r2 = r3;
    }
}

// ---- Chunked parallel selective scan (CS=64, 512 blocks) --------------------
__global__ __launch_bounds__(256) void scan_pass1(
    const unsigned short* __restrict__ xc16, const float* __restrict__ delta,
    const float* __restrict__ dbc, const float* __restrict__ A_log,
    float* __restrict__ P, float* __restrict__ E)
{
    __shared__ float Bs[CS * DSTATE];
    const int tid = threadIdx.x;
    const int db  = blockIdx.x & 7;
    const int c   = (blockIdx.x >> 3) & (NCH - 1);
    const int b   = blockIdx.x >> 8;
    const int d   = db * 256 + tid;
    const int t0  = b * L_SZ + c * CS;

    for (int idx = tid; idx < CS * DSTATE; idx += 256) {
        int step = idx >> 4, i = idx & 15;
        Bs[idx] = dbc[(t0 + step) * 96 + DTRANK + i];
    }

    float A[DSTATE], Er[DSTATE];
    #pragma unroll
    for (int s = 0; s < DSTATE; s++) {
        A[s]  = -__expf(A_log[d * DSTATE + s]);
        Er[s] = 0.0f;
    }
    float sd = 0.0f;
    __syncthreads();

    for (int l = 0; l < CS; l++) {
        const int t = t0 + l;
        float dv = delta[t * DINNER + d];
        float uv = bf2f(xc16[(size_t)t * DINNER + d]);
        float du = dv * uv;
        sd += dv;
        #pragma unroll
        for (int s = 0; s < DSTATE; s++) {
            float dA = __expf(dv * A[s]);
            Er[s] = dA * Er[s] + du * Bs[l * DSTATE + s];
        }
    }

    const long long o = ((long long)((b * NCH + c) * DINNER) + d) * DSTATE;
    #pragma unroll
    for (int s = 0; s < DSTATE; s++) {
        P[o + s] = __expf(A[s] * sd);
        E[o + s] = Er[s];
    }
}

__global__ __launch_bounds__(256) void scan_pass2(
    const float* __restrict__ P, float* __restrict__ E)
{
    const int gid  = blockIdx.x * 256 + threadIdx.x;
    const int b    = gid >> 15;
    const int rest = gid & 32767;
    float h = 0.0f;
    for (int c = 0; c < NCH; c++) {
        const long long idx = (long long)(b * NCH + c) * (DINNER * DSTATE) + rest;
        float p = P[idx];
        float e = E[idx];
        E[idx] = h;
        h = p * h + e;
    }
}

// pass3: emit y in bf16, fused silu(z) gate (z from bf16 xz cols 2048..4096).
__global__ __launch_bounds__(256) void scan_pass3(
    const unsigned short* __restrict__ xc16, const float* __restrict__ delta,
    const float* __restrict__ dbc, const float* __restrict__ A_log,
    const float* __restrict__ D_skip, const float* __restrict__ Hin,
    const unsigned short* __restrict__ xz16, unsigned short* __restrict__ y16)
{
    __shared__ float BCs[CS * 2 * DSTATE];
    const int tid = threadIdx.x;
    const int db  = blockIdx.x & 7;
    const int c   = (blockIdx.x >> 3) & (NCH - 1);
    const int b   = blockIdx.x >> 8;
    const int d   = db * 256 + tid;
    const int t0  = b * L_SZ + c * CS;

    for (int idx = tid; idx < CS * 2 * DSTATE; idx += 256) {
        int step = idx >> 5, i = idx & 31;
        BCs[idx] = dbc[(t0 + step) * 96 + DTRANK + i];
    }

    float A[DSTATE], h[DSTATE];
    const long long o = ((long long)((b * NCH + c) * DINNER) + d) * DSTATE;
    #pragma unroll
    for (int s = 0; s < DSTATE; s++) {
        A[s] = -__expf(A_log[d * DSTATE + s]);
        h[s] = Hin[o + s];
    }
    const float Dv = D_skip[d];
    __syncthreads();

    for (int l = 0; l < CS; l++) {
        const int t = t0 + l;
        float dv = delta[t * DINNER + d];
        float uv = bf2f(xc16[(size_t)t * DINNER + d]);
        float du = dv * uv;
        float yv = 0.0f;
        #pragma unroll
        for (int s = 0; s < DSTATE; s++) {
            float dA = __expf(dv * A[s]);
            h[s] = dA * h[s] + du * BCs[l * 32 + s];
            yv  += h[s] * BCs[l * 32 + DSTATE + s];
        }
        float z = bf2f(xz16[(size_t)t * 4096 + DINNER + d]);
        y16[t * DINNER + d] = f2bf((uv * Dv + yv) * silu_f(z));
    }
}

extern "C" void kernel_launch(void* const* d_in, const int* in_sizes, int n_in,
                              void* d_out, int out_size, void* d_ws, size_t ws_size,
                              hipStream_t stream) {
    const float* x       = (const float*)d_in[0];
    const float* W_in    = (const float*)d_in[1];
    const float* conv_w  = (const float*)d_in[2];
    const float* conv_b  = (const float*)d_in[3];
    const float* W_xproj = (const float*)d_in[4];
    const float* W_dt    = (const float*)d_in[5];
    const float* b_dt    = (const float*)d_in[6];
    const float* A_log   = (const float*)d_in[7];
    const float* D_skip  = (const float*)d_in[8];
    const float* W_out   = (const float*)d_in[9];
    float* out = (float*)d_out;

    // workspace layout, float units (137 MB) — identical to R8 (proven).
    float* ws = (float*)d_ws;
    unsigned short* xz16   = (unsigned short*)ws;              // [0 .. 8388608) f
    unsigned short* xc16   = (unsigned short*)(ws +  8388608); // [.. 12582912) f
    float* dbc             = ws + 12582912;                    // [.. 12976128) f
    unsigned short* dtlo16 = (unsigned short*)(ws + 12976128); // [.. 13107200) f
    float* delta           = ws + 13107200;                    // [.. 21495808) f
    float* Ebuf            = ws + 21495808;                    // [.. 23592960) f (becomes Hin)
    float* parts           = ws + 23592960;                    // [.. 26738688) f
    float* Pbuf            = parts;                            //   alias (parts dead after reduce)
    unsigned short* yb16   = (unsigned short*)(ws + 26738688); // [.. 30932992) f
    unsigned short* x16    = yb16;                             //   alias (x16 dead after gemm1)
    unsigned short* W_inT    = (unsigned short*)(ws + 30932992);
    unsigned short* W_xprojT = (unsigned short*)(ws + 33030144);
    unsigned short* W_dtT    = (unsigned short*)(ws + 33128448);
    unsigned short* W_outT   = (unsigned short*)(ws + 33193984);

    const int MT = 4096;  // B*L tokens

    transpose_cast<<<dim3(128, 32), 256, 0, stream>>>(W_in,    W_inT,    1024, 4096);
    transpose_cast<<<dim3(  3, 64), 256, 0, stream>>>(W_xproj, W_xprojT, 2048,   96);
    transpose_cast<<<dim3( 64,  2), 256, 0, stream>>>(W_dt,    W_dtT,      64, 2048);
    transpose_cast<<<dim3( 32, 64), 256, 0, stream>>>(W_out,   W_outT,   2048, 1024);
    cast_bf16<<<dim3(2048), 256, 0, stream>>>(x, x16, 524288);

    // 1) xz = x @ W_in              (4096 x 4096, K=1024) -> bf16
    gemm_bt_lds<0, 1><<<dim3(32, 32), 256, 0, stream>>>(
        x16, W_inT, xz16, nullptr, MT, 4096, 1024, 1024, 1024, 4096, 1024);

    // 2) xc16 = silu(causal_dwconv(xin) + b)
    conv_silu_v2<<<dim3(8, 64, 2), 256, 0, stream>>>(xz16, conv_w, conv_b, xc16);

    // 3) dbc = xc @ W_xproj         (4096 x 96, K=2048) — split-K x8
    gemm_bt_lds<0, 0><<<dim3(1, 32, 8), 256, 0, stream>>>(
        xc16, W_xprojT, parts, nullptr, MT, 96, 2048, 2048, 2048, 96, 256);
    reduce_splitk<<<dim3(1536), 256, 0, stream>>>(parts, dbc, dtlo16, MT * 96, 8);

    // 4) delta = softplus(dt_lo @ W_dt + b_dt)  (4096 x 2048, K=64) — fast softplus
    gemm_bt_lds<1, 0><<<dim3(16, 32), 256, 0, stream>>>(
        dtlo16, W_dtT, delta, b_dt, MT, 2048, 64, 64, 64, 2048, 64);

    // 5) chunked selective scan + fused gate (bf16 y out)
    scan_pass1<<<dim3(512), 256, 0, stream>>>(xc16, delta, dbc, A_log, Pbuf, Ebuf);
    scan_pass2<<<dim3(256), 256, 0, stream>>>(Pbuf, Ebuf);
    scan_pass3<<<dim3(512), 256, 0, stream>>>(xc16, delta, dbc, A_log, D_skip,
                                              Ebuf, xz16, yb16);

    // 6) out = y @ W_out            (4096 x 1024, K=2048)
    gemm_bt_lds<0, 0><<<dim3(8, 32), 256, 0, stream>>>(
        yb16, W_outT, out, nullptr, MT, 1024, 2048, 2048, 2048, 1024, 2048);
}

// Round 12
// 327.821 us; speedup vs baseline: 1.4016x; 1.0477x over previous
//
#include <hip/hip_runtime.h>
#include <math.h>

#define B_SZ 2
#define L_SZ 2048
#define DMODEL 1024
#define DINNER 2048
#define DSTATE 16
#define DCONV 4
#define DTRANK 64

#define CS 32                    // scan chunk size
#define NCH (L_SZ / CS)          // 64 chunks per batch

typedef float f32x4 __attribute__((ext_vector_type(4)));
typedef __bf16 bf16x8 __attribute__((ext_vector_type(8)));

__device__ __forceinline__ float silu_f(float x) {
    return x / (1.0f + __expf(-x));
}

// fast softplus: max(x,0) + log(1+exp(-|x|)); abs err ~1e-6, branch-free tails
__device__ __forceinline__ float softplus_f(float x) {
    return fmaxf(x, 0.0f) + __logf(1.0f + __expf(-fabsf(x)));
}

// fp32 -> bf16 round-to-nearest-even on raw bits
__device__ __forceinline__ unsigned short f2bf(float x) {
    unsigned int u = __float_as_uint(x);
    u = u + 0x7FFFu + ((u >> 16) & 1u);
    return (unsigned short)(u >> 16);
}

__device__ __forceinline__ float bf2f(unsigned short s) {
    return __uint_as_float(((unsigned int)s) << 16);
}

// async global->LDS DMA, 16B per lane; deposits at base + lane*16B.
__device__ __forceinline__ void gload_lds16(const unsigned short* g, unsigned short* l) {
    __builtin_amdgcn_global_load_lds(
        (const __attribute__((address_space(1))) void*)g,
        (__attribute__((address_space(3))) void*)l, 16, 0, 0);
}

union Pack8 { unsigned short s[8]; uint4 v; };

// Transpose + cast: W[R,C] fp32 -> WT[C,R] bf16. Grid (C/32, R/32), 256 thr.
__global__ __launch_bounds__(256) void transpose_cast(
    const float* __restrict__ W, unsigned short* __restrict__ WT, int R, int C)
{
    __shared__ float t[32][33];
    const int tx = threadIdx.x & 31;
    const int ty = threadIdx.x >> 5;
    const int r0 = blockIdx.y * 32;
    const int c0 = blockIdx.x * 32;
    #pragma unroll
    for (int i = 0; i < 4; i++)
        t[ty + i * 8][tx] = W[(r0 + ty + i * 8) * C + c0 + tx];
    __syncthreads();
    #pragma unroll
    for (int i = 0; i < 4; i++)
        WT[(c0 + ty + i * 8) * R + r0 + tx] = f2bf(t[tx][ty + i * 8]);
}

// cast fp32 -> bf16, 8 elems/thread
__global__ __launch_bounds__(256) void cast_bf16(
    const float* __restrict__ src, unsigned short* __restrict__ dst, int n8)
{
    int i = blockIdx.x * 256 + threadIdx.x;
    if (i >= n8) return;
    const float4 f0 = *(const float4*)(src + i * 8);
    const float4 f1 = *(const float4*)(src + i * 8 + 4);
    Pack8 p;
    p.s[0] = f2bf(f0.x); p.s[1] = f2bf(f0.y); p.s[2] = f2bf(f0.z); p.s[3] = f2bf(f0.w);
    p.s[4] = f2bf(f1.x); p.s[5] = f2bf(f1.y); p.s[6] = f2bf(f1.z); p.s[7] = f2bf(f1.w);
    *(uint4*)(dst + i * 8) = p.v;
}

// ---- bf16 MFMA GEMM, B pre-transposed, global_load_lds staging -------------
// C[M,N] = A[M,K](bf16) @ BT[N,K](bf16)^T, fp32 accumulate.
// BK=64, XOR-swizzled LDS (conflict-free b128 reads, no padding needed).
// Tile 128x128, 4 waves (2x2), 64x64/wave via mfma_f32_16x16x32_bf16.
// Split-K via gridDim.z (Kc multiple of 64). B row clamped to N-1.
template <int ACT, int OBF16>
__global__ __launch_bounds__(256) void gemm_bt_lds(
    const unsigned short* __restrict__ A, const unsigned short* __restrict__ BT,
    void* __restrict__ Cout, const float* __restrict__ bias,
    int M, int N, int K, int lda, int ldb, int ldc, int Kc)
{
    __shared__ unsigned short As[128 * 64];
    __shared__ unsigned short Bs[128 * 64];

    const int tid  = threadIdx.x;
    const int lane = tid & 63;
    const int wave = tid >> 6;
    const int wm   = wave >> 1;
    const int wn   = wave & 1;
    const int row0 = blockIdx.y * 128;
    const int col0 = blockIdx.x * 128;
    const int lq   = lane >> 4;
    const int lm   = lane & 15;
    const int kbeg = blockIdx.z * Kc;

    const int rloc = wave * 32 + (lane >> 3);
    const int sc   = (lane & 7) ^ ((lane >> 3) & 7);
    const unsigned short* gA = A + (size_t)(row0 + rloc) * lda + sc * 8;
    const unsigned short* gBp[4];
    #pragma unroll
    for (int is = 0; is < 4; is++) {
        int br = col0 + rloc + 8 * is;
        if (br > N - 1) br = N - 1;
        gBp[is] = BT + (size_t)br * ldb + sc * 8;
    }
    unsigned short* lA = As + wave * 2048;
    unsigned short* lB = Bs + wave * 2048;

    f32x4 acc[4][4];
    #pragma unroll
    for (int i = 0; i < 4; i++)
        #pragma unroll
        for (int j = 0; j < 4; j++)
            #pragma unroll
            for (int r = 0; r < 4; r++) acc[i][j][r] = 0.0f;

    for (int k0 = kbeg; k0 < kbeg + Kc; k0 += 64) {
        #pragma unroll
        for (int is = 0; is < 4; is++) {
            gload_lds16(gA + (size_t)(8 * is) * lda + k0, lA + is * 512);
            gload_lds16(gBp[is] + k0, lB + is * 512);
        }
        __syncthreads();

        #pragma unroll
        for (int ks = 0; ks < 2; ks++) {
            bf16x8 af[4], bfr[4];
            #pragma unroll
            for (int i = 0; i < 4; i++) {
                int row = wm * 64 + i * 16 + lm;
                af[i] = *(const bf16x8*)&As[row * 64 + (((ks * 4 + lq) ^ (row & 7)) * 8)];
            }
            #pragma unroll
            for (int j = 0; j < 4; j++) {
                int row = wn * 64 + j * 16 + lm;
                bfr[j] = *(const bf16x8*)&Bs[row * 64 + (((ks * 4 + lq) ^ (row & 7)) * 8)];
            }
            #pragma unroll
            for (int i = 0; i < 4; i++)
                #pragma unroll
                for (int j = 0; j < 4; j++)
                    acc[i][j] = __builtin_amdgcn_mfma_f32_16x16x32_bf16(
                        af[i], bfr[j], acc[i][j], 0, 0, 0);
        }
        __syncthreads();
    }

    // epilogue: C/D layout col=lane&15, row=(lane>>4)*4+reg
    #pragma unroll
    for (int i = 0; i < 4; i++) {
        #pragma unroll
        for (int r = 0; r < 4; r++) {
            int row = row0 + wm * 64 + i * 16 + lq * 4 + r;
            #pragma unroll
            for (int j = 0; j < 4; j++) {
                int col = col0 + wn * 64 + j * 16 + lm;
                if (col < N) {
                    float v = acc[i][j][r];
                    if (ACT == 1) v = softplus_f(v + bias[col]);
                    if (OBF16) {
                        unsigned short* Cz = (unsigned short*)Cout +
                            (size_t)blockIdx.z * (size_t)M * ldc;
                        Cz[(size_t)row * ldc + col] = f2bf(v);
                    } else {
                        float* Cz = (float*)Cout +
                            (size_t)blockIdx.z * (size_t)M * ldc;
                        Cz[(size_t)row * ldc + col] = v;
                    }
                }
            }
        }
    }
}

// Sum nsplit partial C buffers; also emit bf16 copy of cols<64 (dt_lo).
__global__ __launch_bounds__(256) void reduce_splitk(
    const float* __restrict__ part, float* __restrict__ C,
    unsigned short* __restrict__ dtlo16, int n, int nsplit)
{
    int i = blockIdx.x * 256 + threadIdx.x;
    if (i >= n) return;
    float s = 0.0f;
    for (int z = 0; z < nsplit; z++) s += part[(size_t)z * n + i];
    C[i] = s;
    int row = i / 96;
    int col = i - row * 96;
    if (col < DTRANK) dtlo16[row * DTRANK + col] = f2bf(s);
}

// conv + silu, register-rolling window along l. Reads bf16 xz (cols 0..2048),
// emits bf16 xc16. grid (8, 64, 2).
__global__ __launch_bounds__(256) void conv_silu_v2(
    const unsigned short* __restrict__ xz16, const float* __restrict__ conv_w,
    const float* __restrict__ conv_b, unsigned short* __restrict__ xc16)
{
    const int tid = threadIdx.x;
    const int d   = blockIdx.x * 256 + tid;
    const int l0  = blockIdx.y * 32;
    const int b   = blockIdx.z;
    const float4 w  = *(const float4*)(conv_w + d * 4);
    const float bias = conv_b[d];
    const int t0 = b * L_SZ + l0;
    const unsigned short* src = xz16 + (size_t)t0 * 4096 + d;

    float r0, r1, r2;
    if (l0 == 0) {
        r0 = r1 = r2 = 0.0f;
    } else {
        r0 = bf2f(src[-3 * 4096]);
        r1 = bf2f(src[-2 * 4096]);
        r2 = bf2f(src[-1 * 4096]);
    }
    #pragma unroll 4
    for (int l = 0; l < 32; l++) {
        float r3 = bf2f(src[(size_t)l * 4096]);
        float acc = bias + r0 * w.x + r1 * w.y + r2 * w.z + r3 * w.w;
        xc16[(size_t)(t0 + l) * DINNER + d] = f2bf(silu_f(acc));
        r0 = r1; r1 = r2; r2 = r3;
    }
}

// ---- Chunked parallel selective scan (CS=32, 1024 blocks) -------------------
// grid: B * NCH * 8 = 2*64*8 = 1024; db=blk&7, c=(blk>>3)&63, b=blk>>9.
__global__ __launch_bounds__(256) void scan_pass1(
    const unsigned short* __restrict__ xc16, const float* __restrict__ delta,
    const float* __restrict__ dbc, const float* __restrict__ A_log,
    float* __restrict__ P, float* __restrict__ E)
{
    __shared__ float Bs[CS * DSTATE];
    const int tid = threadIdx.x;
    const int db  = blockIdx.x & 7;
    const int c   = (blockIdx.x >> 3) & (NCH - 1);
    const int b   = blockIdx.x >> 9;
    const int d   = db * 256 + tid;
    const int t0  = b * L_SZ + c * CS;

    for (int idx = tid; idx < CS * DSTATE; idx += 256) {
        int step = idx >> 4, i = idx & 15;
        Bs[idx] = dbc[(t0 + step) * 96 + DTRANK + i];
    }

    float A[DSTATE], Er[DSTATE];
    #pragma unroll
    for (int s = 0; s < DSTATE; s++) {
        A[s]  = -__expf(A_log[d * DSTATE + s]);
        Er[s] = 0.0f;
    }
    float sd = 0.0f;
    __syncthreads();

    for (int l = 0; l < CS; l++) {
        const int t = t0 + l;
        float dv = delta[t * DINNER + d];
        float uv = bf2f(xc16[(size_t)t * DINNER + d]);
        float du = dv * uv;
        sd += dv;
        #pragma unroll
        for (int s = 0; s < DSTATE; s++) {
            float dA = __expf(dv * A[s]);
            Er[s] = dA * Er[s] + du * Bs[l * DSTATE + s];
        }
    }

    const long long o = ((long long)((b * NCH + c) * DINNER) + d) * DSTATE;
    #pragma unroll
    for (int s = 0; s < DSTATE; s++) {
        P[o + s] = __expf(A[s] * sd);
        E[o + s] = Er[s];
    }
}

__global__ __launch_bounds__(256) void scan_pass2(
    const float* __restrict__ P, float* __restrict__ E)
{
    const int gid  = blockIdx.x * 256 + threadIdx.x;
    const int b    = gid >> 15;
    const int rest = gid & 32767;
    float h = 0.0f;
    for (int c = 0; c < NCH; c++) {
        const long long idx = (long long)(b * NCH + c) * (DINNER * DSTATE) + rest;
        float p = P[idx];
        float e = E[idx];
        E[idx] = h;
        h = p * h + e;
    }
}

// pass3: emit y in bf16, fused silu(z) gate (z from bf16 xz cols 2048..4096).
__global__ __launch_bounds__(256) void scan_pass3(
    const unsigned short* __restrict__ xc16, const float* __restrict__ delta,
    const float* __restrict__ dbc, const float* __restrict__ A_log,
    const float* __restrict__ D_skip, const float* __restrict__ Hin,
    const unsigned short* __restrict__ xz16, unsigned short* __restrict__ y16)
{
    __shared__ float BCs[CS * 2 * DSTATE];
    const int tid = threadIdx.x;
    const int db  = blockIdx.x & 7;
    const int c   = (blockIdx.x >> 3) & (NCH - 1);
    const int b   = blockIdx.x >> 9;
    const int d   = db * 256 + tid;
    const int t0  = b * L_SZ + c * CS;

    for (int idx = tid; idx < CS * 2 * DSTATE; idx += 256) {
        int step = idx >> 5, i = idx & 31;
        BCs[idx] = dbc[(t0 + step) * 96 + DTRANK + i];
    }

    float A[DSTATE], h[DSTATE];
    const long long o = ((long long)((b * NCH + c) * DINNER) + d) * DSTATE;
    #pragma unroll
    for (int s = 0; s < DSTATE; s++) {
        A[s] = -__expf(A_log[d * DSTATE + s]);
        h[s] = Hin[o + s];
    }
    const float Dv = D_skip[d];
    __syncthreads();

    for (int l = 0; l < CS; l++) {
        const int t = t0 + l;
        float dv = delta[t * DINNER + d];
        float uv = bf2f(xc16[(size_t)t * DINNER + d]);
        float du = dv * uv;
        float yv = 0.0f;
        #pragma unroll
        for (int s = 0; s < DSTATE; s++) {
            float dA = __expf(dv * A[s]);
            h[s] = dA * h[s] + du * BCs[l * 32 + s];
            yv  += h[s] * BCs[l * 32 + DSTATE + s];
        }
        float z = bf2f(xz16[(size_t)t * 4096 + DINNER + d]);
        y16[t * DINNER + d] = f2bf((uv * Dv + yv) * silu_f(z));
    }
}

extern "C" void kernel_launch(void* const* d_in, const int* in_sizes, int n_in,
                              void* d_out, int out_size, void* d_ws, size_t ws_size,
                              hipStream_t stream) {
    const float* x       = (const float*)d_in[0];
    const float* W_in    = (const float*)d_in[1];
    const float* conv_w  = (const float*)d_in[2];
    const float* conv_b  = (const float*)d_in[3];
    const float* W_xproj = (const float*)d_in[4];
    const float* W_dt    = (const float*)d_in[5];
    const float* b_dt    = (const float*)d_in[6];
    const float* A_log   = (const float*)d_in[7];
    const float* D_skip  = (const float*)d_in[8];
    const float* W_out   = (const float*)d_in[9];
    float* out = (float*)d_out;

    // workspace layout, float units (141 MB). Aliases (dead-before-reuse):
    //   parts (dead after reduce) shares Pbuf (written at pass1)
    //   x16 (dead after gemm1)    shares yb16 (written at pass3)
    float* ws = (float*)d_ws;
    unsigned short* xz16   = (unsigned short*)ws;              // [0 .. 8388608) f
    unsigned short* xc16   = (unsigned short*)(ws +  8388608); // [.. 12582912) f
    float* dbc             = ws + 12582912;                    // [.. 12976128) f
    unsigned short* dtlo16 = (unsigned short*)(ws + 12976128); // [.. 13107200) f
    float* delta           = ws + 13107200;                    // [.. 21495808) f
    float* Ebuf            = ws + 21495808;                    // [.. 25690112) f : 2*64*2048*16
    float* Pbuf            = ws + 25690112;                    // [.. 29884416) f : 2*64*2048*16
    float* parts           = Pbuf;                             //   alias, 3145728 f < 4194304 ✓
    unsigned short* yb16   = (unsigned short*)(ws + 29884416); // [.. 31981568) f
    unsigned short* x16    = yb16;                             //   alias
    unsigned short* W_inT    = (unsigned short*)(ws + 31981568); // [.. 34078720) f
    unsigned short* W_xprojT = (unsigned short*)(ws + 34078720); // [.. 34177024) f
    unsigned short* W_dtT    = (unsigned short*)(ws + 34177024); // [.. 34242560) f
    unsigned short* W_outT   = (unsigned short*)(ws + 34242560); // [.. 35291136) f

    const int MT = 4096;  // B*L tokens

    transpose_cast<<<dim3(128, 32), 256, 0, stream>>>(W_in,    W_inT,    1024, 4096);
    transpose_cast<<<dim3(  3, 64), 256, 0, stream>>>(W_xproj, W_xprojT, 2048,   96);
    transpose_cast<<<dim3( 64,  2), 256, 0, stream>>>(W_dt,    W_dtT,      64, 2048);
    transpose_cast<<<dim3( 32, 64), 256, 0, stream>>>(W_out,   W_outT,   2048, 1024);
    cast_bf16<<<dim3(2048), 256, 0, stream>>>(x, x16, 524288);

    // 1) xz = x @ W_in              (4096 x 4096, K=1024) -> bf16
    gemm_bt_lds<0, 1><<<dim3(32, 32), 256, 0, stream>>>(
        x16, W_inT, xz16, nullptr, MT, 4096, 1024, 1024, 1024, 4096, 1024);

    // 2) xc16 = silu(causal_dwconv(xin) + b)
    conv_silu_v2<<<dim3(8, 64, 2), 256, 0, stream>>>(xz16, conv_w, conv_b, xc16);

    // 3) dbc = xc @ W_xproj         (4096 x 96, K=2048) — split-K x8
    gemm_bt_lds<0, 0><<<dim3(1, 32, 8), 256, 0, stream>>>(
        xc16, W_xprojT, parts, nullptr, MT, 96, 2048, 2048, 2048, 96, 256);
    reduce_splitk<<<dim3(1536), 256, 0, stream>>>(parts, dbc, dtlo16, MT * 96, 8);

    // 4) delta = softplus(dt_lo @ W_dt + b_dt)  (4096 x 2048, K=64) — fast softplus
    gemm_bt_lds<1, 0><<<dim3(16, 32), 256, 0, stream>>>(
        dtlo16, W_dtT, delta, b_dt, MT, 2048, 64, 64, 64, 2048, 64);

    // 5) chunked selective scan + fused gate (bf16 y out)
    scan_pass1<<<dim3(1024), 256, 0, stream>>>(xc16, delta, dbc, A_log, Pbuf, Ebuf);
    scan_pass2<<<dim3(256), 256, 0, stream>>>(Pbuf, Ebuf);
    scan_pass3<<<dim3(1024), 256, 0, stream>>>(xc16, delta, dbc, A_log, D_skip,
                                               Ebuf, xz16, yb16);

    // 6) out = y @ W_out            (4096 x 1024, K=2048)
    gemm_bt_lds<0, 0><<<dim3(8, 32), 256, 0, stream>>>(
        yb16, W_outT, out, nullptr, MT, 1024, 2048, 2048, 2048, 1024, 2048);
}